// Round 1
// baseline (449.575 us; speedup 1.0000x reference)
//
#include <hip/hip_runtime.h>

#define EMBED 1024
#define HID   4096
#define NB    4
#define SEQ   2048

typedef __attribute__((ext_vector_type(8))) __bf16 bf16x8;
typedef __attribute__((ext_vector_type(4))) float  f32x4;
typedef __attribute__((ext_vector_type(4))) int    i32x4;
typedef unsigned short u16;

__device__ __forceinline__ u16 f2bf(float f) {
  unsigned u = __float_as_uint(f);
  u += 0x7FFFu + ((u >> 16) & 1u);
  return (u16)(u >> 16);
}

typedef const __attribute__((address_space(1))) unsigned int* gas_t;
typedef __attribute__((address_space(3))) unsigned int* las_t;
__device__ __forceinline__ void gld16(const void* g, void* l) {
  // async global->LDS, 16B per lane; LDS dest is wave-uniform base + lane*16
  __builtin_amdgcn_global_load_lds((gas_t)g, (las_t)l, 16, 0, 0);
}

// ---------------------------------------------------------------------------
// NT GEMM: C[m][n] = sum_k A[m][k] * B[n][k]   (A,B bf16 row-major over k)
// 128x128 tile, BK=64, 4 waves (2x2), 16x16x32 bf16 MFMA, global_load_lds
// staging with XOR chunk swizzle (pre-swizzled global source, swizzled read).
// EPI: 0 = bias->bf16 (QKV)   1 = *scale->f32 (scores)
//      2 = +add->f32 (PV + residual)  3 = bias,relu->bf16 (MLP1)
//      4 = bias,+add->f32 (MLP2 + residual -> out)
// ---------------------------------------------------------------------------
template<int EPI>
__global__ __launch_bounds__(256) void gemm_nt(
    const u16* __restrict__ A, int lda, long long astr,
    const u16* __restrict__ B, int ldb, long long bstr,
    void* __restrict__ C, int ldc, long long cstr,
    const float* __restrict__ bias,
    const float* __restrict__ add,
    float scale, int Kdim)
{
  __shared__ i32x4 As4[1024];  // [128 rows][8 chunks of 16B]
  __shared__ i32x4 Bs4[1024];

  const int tid  = threadIdx.x;
  const int lane = tid & 63;
  const int w    = tid >> 6;      // wave 0..3
  const int wr   = w >> 1, wc = w & 1;
  const int l15  = lane & 15, l4 = lane >> 4;

  const u16* Ab = A + (size_t)blockIdx.z * astr + (size_t)blockIdx.y * 128 * lda;
  const u16* Bb = B + (size_t)blockIdx.z * bstr + (size_t)blockIdx.x * 128 * ldb;

  f32x4 acc[4][4] = {};

  for (int k0 = 0; k0 < Kdim; k0 += 64) {
    // ---- stage A,B tiles (each wave: rows [w*32, w*32+32), 4 issues each) --
    #pragma unroll
    for (int i = 0; i < 4; ++i) {
      const int c   = (w * 4 + i) * 64 + lane;   // linear chunk 0..1023
      const int row = c >> 3;
      const int gc  = (c & 7) ^ (row & 7);       // inverse-swizzled source chunk
      gld16(Ab + (size_t)row * lda + (k0 + gc * 8), &As4[(w * 4 + i) * 64]);
      gld16(Bb + (size_t)row * ldb + (k0 + gc * 8), &Bs4[(w * 4 + i) * 64]);
    }
    __syncthreads();
    // ---- compute: 2 k-steps of 32, 16 MFMA each --------------------------
    #pragma unroll
    for (int ks = 0; ks < 2; ++ks) {
      bf16x8 af[4], bfr[4];
      #pragma unroll
      for (int mi = 0; mi < 4; ++mi) {
        const int row = wr * 64 + mi * 16 + l15;
        const int cp  = (ks * 4 + l4) ^ (row & 7);
        af[mi] = __builtin_bit_cast(bf16x8, As4[row * 8 + cp]);
      }
      #pragma unroll
      for (int ni = 0; ni < 4; ++ni) {
        const int row = wc * 64 + ni * 16 + l15;
        const int cp  = (ks * 4 + l4) ^ (row & 7);
        bfr[ni] = __builtin_bit_cast(bf16x8, Bs4[row * 8 + cp]);
      }
      #pragma unroll
      for (int mi = 0; mi < 4; ++mi)
        #pragma unroll
        for (int ni = 0; ni < 4; ++ni)
          acc[mi][ni] = __builtin_amdgcn_mfma_f32_16x16x32_bf16(
              af[mi], bfr[ni], acc[mi][ni], 0, 0, 0);
    }
    __syncthreads();
  }

  // ---- epilogue: C/D layout col=lane&15, row=(lane>>4)*4+reg (m89) --------
  const int bm0 = blockIdx.y * 128 + wr * 64;
  const int bn0 = blockIdx.x * 128 + wc * 64;
  float* Cf = (float*)C;
  u16*   Ch = (u16*)C;
  #pragma unroll
  for (int mi = 0; mi < 4; ++mi) {
    #pragma unroll
    for (int ni = 0; ni < 4; ++ni) {
      const int col = bn0 + ni * 16 + l15;
      const int r0  = bm0 + mi * 16 + l4 * 4;
      float bv = 0.f;
      if (EPI == 0 || EPI == 3 || EPI == 4) bv = bias[col];
      #pragma unroll
      for (int r = 0; r < 4; ++r) {
        const size_t idx = (size_t)blockIdx.z * cstr + (size_t)(r0 + r) * ldc + col;
        const float v = acc[mi][ni][r];
        if      (EPI == 0) Ch[idx] = f2bf(v + bv);
        else if (EPI == 1) Cf[idx] = v * scale;
        else if (EPI == 2) Cf[idx] = v + add[idx];
        else if (EPI == 3) Ch[idx] = f2bf(fmaxf(v + bv, 0.f));
        else               Cf[idx] = v + bv + add[idx];
      }
    }
  }
}

// ---------------------------------------------------------------------------
// LayerNorm row kernel: x f32 [rows][1024] -> bf16 out, per-row mean/var
// ---------------------------------------------------------------------------
__global__ __launch_bounds__(256) void ln_kernel(
    const float* __restrict__ x, const float* __restrict__ g,
    const float* __restrict__ be, u16* __restrict__ out)
{
  const int row = blockIdx.x;
  const int tid = threadIdx.x;
  const float4 v = ((const float4*)(x + (size_t)row * EMBED))[tid];
  float s  = v.x + v.y + v.z + v.w;
  float s2 = v.x * v.x + v.y * v.y + v.z * v.z + v.w * v.w;
  #pragma unroll
  for (int m = 1; m < 64; m <<= 1) { s += __shfl_xor(s, m); s2 += __shfl_xor(s2, m); }
  __shared__ float ls[4], ls2[4];
  const int w = tid >> 6;
  if ((tid & 63) == 0) { ls[w] = s; ls2[w] = s2; }
  __syncthreads();
  s  = ls[0] + ls[1] + ls[2] + ls[3];
  s2 = ls2[0] + ls2[1] + ls2[2] + ls2[3];
  const float mu   = s * (1.f / EMBED);
  const float var  = s2 * (1.f / EMBED) - mu * mu;
  const float rstd = rsqrtf(var + 1e-5f);
  const float4 gv = ((const float4*)g)[tid];
  const float4 bv = ((const float4*)be)[tid];
  ushort4 o;
  o.x = f2bf((v.x - mu) * rstd * gv.x + bv.x);
  o.y = f2bf((v.y - mu) * rstd * gv.y + bv.y);
  o.z = f2bf((v.z - mu) * rstd * gv.z + bv.z);
  o.w = f2bf((v.w - mu) * rstd * gv.w + bv.w);
  ((ushort4*)(out + (size_t)row * EMBED))[tid] = o;
}

// ---------------------------------------------------------------------------
// Row softmax: S f32 [2048] -> P bf16, rows = grid.x, batch = grid.y
// ---------------------------------------------------------------------------
__global__ __launch_bounds__(256) void softmax_kernel(
    const float* __restrict__ S, u16* __restrict__ P)
{
  const int tid = threadIdx.x;
  const size_t base = ((size_t)blockIdx.y * SEQ + blockIdx.x) * SEQ;
  const float4* src = (const float4*)(S + base);
  float4 a = src[tid];
  float4 b = src[tid + 256];
  float m = fmaxf(fmaxf(fmaxf(a.x, a.y), fmaxf(a.z, a.w)),
                  fmaxf(fmaxf(b.x, b.y), fmaxf(b.z, b.w)));
  #pragma unroll
  for (int msk = 1; msk < 64; msk <<= 1) m = fmaxf(m, __shfl_xor(m, msk));
  __shared__ float red[8];
  const int w = tid >> 6;
  if ((tid & 63) == 0) red[w] = m;
  __syncthreads();
  m = fmaxf(fmaxf(red[0], red[1]), fmaxf(red[2], red[3]));
  a.x = __expf(a.x - m); a.y = __expf(a.y - m); a.z = __expf(a.z - m); a.w = __expf(a.w - m);
  b.x = __expf(b.x - m); b.y = __expf(b.y - m); b.z = __expf(b.z - m); b.w = __expf(b.w - m);
  float s = a.x + a.y + a.z + a.w + b.x + b.y + b.z + b.w;
  #pragma unroll
  for (int msk = 1; msk < 64; msk <<= 1) s += __shfl_xor(s, msk);
  if ((tid & 63) == 0) red[4 + w] = s;
  __syncthreads();
  s = red[4] + red[5] + red[6] + red[7];
  const float inv = 1.0f / s;
  ushort4 oa, ob;
  oa.x = f2bf(a.x * inv); oa.y = f2bf(a.y * inv); oa.z = f2bf(a.z * inv); oa.w = f2bf(a.w * inv);
  ob.x = f2bf(b.x * inv); ob.y = f2bf(b.y * inv); ob.z = f2bf(b.z * inv); ob.w = f2bf(b.w * inv);
  ushort4* dst = (ushort4*)(P + base);
  dst[tid]       = oa;
  dst[tid + 256] = ob;
}

// ---------------------------------------------------------------------------
// Transpose + cast: W f32 [K][N] -> Wt bf16 [N][K]
// ---------------------------------------------------------------------------
__global__ void transpose_cast_f32(const float* __restrict__ W, u16* __restrict__ Wt,
                                   int K, int N)
{
  __shared__ float t[32][33];
  const int tx = threadIdx.x, ty = threadIdx.y;     // 32 x 8
  const int n0 = blockIdx.x * 32, k0 = blockIdx.y * 32;
  #pragma unroll
  for (int i = 0; i < 4; ++i)
    t[ty + i * 8][tx] = W[(size_t)(k0 + ty + i * 8) * N + n0 + tx];
  __syncthreads();
  #pragma unroll
  for (int i = 0; i < 4; ++i)
    Wt[(size_t)(n0 + ty + i * 8) * K + k0 + tx] = f2bf(t[tx][ty + i * 8]);
}

// Transpose bf16: V [SEQ][EMBED] -> Vt [EMBED][SEQ], batched over grid.z
__global__ void transpose_bf16(const u16* __restrict__ V, u16* __restrict__ Vt)
{
  __shared__ u16 t[32][33];
  const int tx = threadIdx.x, ty = threadIdx.y;
  const size_t zoff = (size_t)blockIdx.z * SEQ * EMBED;
  const int d0 = blockIdx.x * 32, s0 = blockIdx.y * 32;
  #pragma unroll
  for (int i = 0; i < 4; ++i)
    t[ty + i * 8][tx] = V[zoff + (size_t)(s0 + ty + i * 8) * EMBED + d0 + tx];
  __syncthreads();
  #pragma unroll
  for (int i = 0; i < 4; ++i)
    Vt[zoff + (size_t)(d0 + ty + i * 8) * SEQ + s0 + tx] = t[tx][ty + i * 8];
}

// ---------------------------------------------------------------------------
extern "C" void kernel_launch(void* const* d_in, const int* in_sizes, int n_in,
                              void* d_out, int out_size, void* d_ws, size_t ws_size,
                              hipStream_t stream)
{
  const float* x   = (const float*)d_in[0];
  const float* Wq  = (const float*)d_in[1];
  const float* bq  = (const float*)d_in[2];
  const float* Wk  = (const float*)d_in[3];
  const float* bk  = (const float*)d_in[4];
  const float* Wv  = (const float*)d_in[5];
  const float* bv  = (const float*)d_in[6];
  const float* W1  = (const float*)d_in[7];
  const float* b1  = (const float*)d_in[8];
  const float* W2  = (const float*)d_in[9];
  const float* b2  = (const float*)d_in[10];
  const float* g1  = (const float*)d_in[11];
  const float* be1 = (const float*)d_in[12];
  const float* g2  = (const float*)d_in[13];
  const float* be2 = (const float*)d_in[14];
  float* out = (float*)d_out;

  const size_t RD = (size_t)NB * SEQ * EMBED;   // 8.4M elements

  char* base = (char*)d_ws;
  size_t o = 0;
  auto alloc = [&](size_t bytes) -> void* {
    o = (o + 255) & ~(size_t)255;
    void* p = base + o;
    o += bytes;
    return p;
  };

  u16* wqT = (u16*)alloc((size_t)EMBED * EMBED * 2);
  u16* wkT = (u16*)alloc((size_t)EMBED * EMBED * 2);
  u16* wvT = (u16*)alloc((size_t)EMBED * EMBED * 2);
  u16* w1T = (u16*)alloc((size_t)HID * EMBED * 2);   // [HID][EMBED]
  u16* w2T = (u16*)alloc((size_t)EMBED * HID * 2);   // [EMBED][HID]
  u16* h   = (u16*)alloc(RD * 2);                    // LN output (reused for LN2)
  u16* Qb  = (u16*)alloc(RD * 2);
  u16* Kb  = (u16*)alloc(RD * 2);
  u16* Vb  = (u16*)alloc(RD * 2);
  u16* Vt  = (u16*)alloc(RD * 2);
  float* x2 = (float*)alloc(RD * 4);                 // x + attn (residual)
  u16* ff  = Qb;  // MLP hidden (64MB) aliases Q,K,V,Vt (dead after attention)

  // batched attention scratch if workspace allows, else per-batch sequential
  const size_t need_batched = o + (size_t)NB * SEQ * SEQ * 6 + 1024;
  const int NZ = (ws_size >= need_batched) ? NB : 1;
  float* Sbuf = (float*)alloc((size_t)NZ * SEQ * SEQ * 4);
  u16*   Pb   = (u16*)alloc((size_t)NZ * SEQ * SEQ * 2);

  const dim3 blk(256);
  const dim3 tblk(32, 8);

  // 1) weight transpose+cast to bf16 [N][K]
  transpose_cast_f32<<<dim3(EMBED / 32, EMBED / 32), tblk, 0, stream>>>(Wq, wqT, EMBED, EMBED);
  transpose_cast_f32<<<dim3(EMBED / 32, EMBED / 32), tblk, 0, stream>>>(Wk, wkT, EMBED, EMBED);
  transpose_cast_f32<<<dim3(EMBED / 32, EMBED / 32), tblk, 0, stream>>>(Wv, wvT, EMBED, EMBED);
  transpose_cast_f32<<<dim3(HID / 32, EMBED / 32), tblk, 0, stream>>>(W1, w1T, EMBED, HID);
  transpose_cast_f32<<<dim3(EMBED / 32, HID / 32), tblk, 0, stream>>>(W2, w2T, HID, EMBED);

  // 2) LN1: x -> h (bf16)
  ln_kernel<<<dim3(NB * SEQ), blk, 0, stream>>>(x, g1, be1, h);

  // 3) QKV projections
  gemm_nt<0><<<dim3(EMBED / 128, NB * SEQ / 128, 1), blk, 0, stream>>>(
      h, EMBED, 0LL, wqT, EMBED, 0LL, Qb, EMBED, 0LL, bq, nullptr, 1.f, EMBED);
  gemm_nt<0><<<dim3(EMBED / 128, NB * SEQ / 128, 1), blk, 0, stream>>>(
      h, EMBED, 0LL, wkT, EMBED, 0LL, Kb, EMBED, 0LL, bk, nullptr, 1.f, EMBED);
  gemm_nt<0><<<dim3(EMBED / 128, NB * SEQ / 128, 1), blk, 0, stream>>>(
      h, EMBED, 0LL, wvT, EMBED, 0LL, Vb, EMBED, 0LL, bv, nullptr, 1.f, EMBED);

  // 4) V -> Vt (per batch [EMBED][SEQ]) for NT PV gemm
  transpose_bf16<<<dim3(EMBED / 32, SEQ / 32, NB), tblk, 0, stream>>>(Vb, Vt);

  // 5) attention: scores -> softmax -> PV (+ residual into x2)
  for (int b = 0; b < NB; b += NZ) {
    const u16* Qp  = Qb + (size_t)b * SEQ * EMBED;
    const u16* Kp  = Kb + (size_t)b * SEQ * EMBED;
    const u16* Vtp = Vt + (size_t)b * SEQ * EMBED;
    float* x2p     = x2 + (size_t)b * SEQ * EMBED;
    const float* xp = x + (size_t)b * SEQ * EMBED;
    gemm_nt<1><<<dim3(SEQ / 128, SEQ / 128, NZ), blk, 0, stream>>>(
        Qp, EMBED, (long long)SEQ * EMBED, Kp, EMBED, (long long)SEQ * EMBED,
        Sbuf, SEQ, (long long)SEQ * SEQ, nullptr, nullptr, 0.03125f, EMBED);
    softmax_kernel<<<dim3(SEQ, NZ), blk, 0, stream>>>(Sbuf, Pb);
    gemm_nt<2><<<dim3(EMBED / 128, SEQ / 128, NZ), blk, 0, stream>>>(
        Pb, SEQ, (long long)SEQ * SEQ, Vtp, SEQ, (long long)SEQ * EMBED,
        x2p, EMBED, (long long)SEQ * EMBED, nullptr, xp, 1.f, SEQ);
  }

  // 6) LN2: x2 -> h (bf16)
  ln_kernel<<<dim3(NB * SEQ), blk, 0, stream>>>(x2, g2, be2, h);

  // 7) MLP
  gemm_nt<3><<<dim3(HID / 128, NB * SEQ / 128, 1), blk, 0, stream>>>(
      h, EMBED, 0LL, w1T, EMBED, 0LL, ff, HID, 0LL, b1, nullptr, 1.f, EMBED);
  gemm_nt<4><<<dim3(EMBED / 128, NB * SEQ / 128, 1), blk, 0, stream>>>(
      ff, HID, 0LL, w2T, HID, 0LL, out, EMBED, 0LL, b2, x2, 1.f, HID);
}

// Round 2
// 363.875 us; speedup vs baseline: 1.2355x; 1.2355x over previous
//
#include <hip/hip_runtime.h>

#define EMBED 1024
#define HID   4096
#define NB    4
#define SEQ   2048

typedef __attribute__((ext_vector_type(8))) __bf16 bf16x8;
typedef __attribute__((ext_vector_type(4))) float  f32x4;
typedef __attribute__((ext_vector_type(4))) int    i32x4;
typedef unsigned short u16;

__device__ __forceinline__ u16 f2bf(float f) {
  unsigned u = __float_as_uint(f);
  u += 0x7FFFu + ((u >> 16) & 1u);
  return (u16)(u >> 16);
}

typedef const __attribute__((address_space(1))) unsigned int* gas_t;
typedef __attribute__((address_space(3))) unsigned int* las_t;
__device__ __forceinline__ void gld16(const void* g, void* l) {
  // async global->LDS, 16B/lane; LDS dest is wave-uniform base + lane*16
  __builtin_amdgcn_global_load_lds((gas_t)g, (las_t)l, 16, 0, 0);
}

#define RD16(p)       __builtin_bit_cast(bf16x8, *(const i32x4*)(p))
#define MFMA16(a,b,c) __builtin_amdgcn_mfma_f32_16x16x32_bf16(a, b, c, 0, 0, 0)

// ---------------------------------------------------------------------------
// Deep-pipelined NT GEMM: C[m][n] = sum_k A[m][k]*B[n][k]  (bf16, fp32 acc)
// BM=256 BN=128 BK=64, 512 thr (8 waves, 4x2), 3 LDS slots, stage lead = 2
// tiles, vmcnt(6) at tile top (counted, never 0 in steady state), 4 phases
// per tile: {ds_read, stage, barrier, lgkmcnt(0), setprio(1), 8 MFMA}.
// Race-freedom: slot (T+2)%3 (stage target during tile T) was last read in
// tile T-1, whose reads drained before T's top barrier; tile T's own loads
// drained by vmcnt(6)+barrier before any ds_read of tile T.
// EPI: 0 bias->bf16 | 1 *scale->f32 | 2 +add->f32 | 3 bias,relu->bf16
//      4 bias,+add->f32
// ---------------------------------------------------------------------------
template<int EPI>
__global__ __launch_bounds__(512, 2) void gemm8p(
    const u16* __restrict__ A, int lda, long long astr,
    const u16* __restrict__ B, int ldb, long long bstr,
    void* __restrict__ C, int ldc, long long cstr,
    const float* __restrict__ bias,
    const float* __restrict__ add,
    float scale, int Kdim)
{
  __shared__ i32x4 lds4[9216];           // 3 slots x 48KB (A 32KB + B 16KB)
  const int SLOT = 49152;

  const int tid  = threadIdx.x;
  const int lane = tid & 63;
  const int w    = tid >> 6;             // wave 0..7
  const int wr   = w >> 1, wc = w & 1;   // 4x2 wave grid -> 64x64 per wave
  const int l15  = lane & 15, l4 = lane >> 4;

  // T1: XCD-aware block swizzle (all grids are multiples of 8 blocks/slice)
  const int gx   = gridDim.x;
  const int nwg  = gx * gridDim.y;
  const int orig = blockIdx.y * gx + blockIdx.x;
  const int t    = ((nwg & 7) == 0) ? ((orig & 7) * (nwg >> 3) + (orig >> 3)) : orig;
  const int bx   = t % gx, by = t / gx;

  const u16* Ab = A + (size_t)blockIdx.z * astr + (size_t)by * 256 * lda;
  const u16* Bb = B + (size_t)blockIdx.z * bstr + (size_t)bx * 128 * ldb;

  // staging source offsets (pre-swizzled global source, linear LDS dest)
  size_t gaoff[4], gboff[2];
  #pragma unroll
  for (int i = 0; i < 4; ++i) {
    const int idx = i * 512 + tid, row = idx >> 3, gc = (idx & 7) ^ (row & 7);
    gaoff[i] = (size_t)row * lda + gc * 8;
  }
  #pragma unroll
  for (int j = 0; j < 2; ++j) {
    const int idx = j * 512 + tid, row = idx >> 3, gc = (idx & 7) ^ (row & 7);
    gboff[j] = (size_t)row * ldb + gc * 8;
  }

  // LDS read byte-offsets (swizzled): row&7 == l15&7 for all fragments
  int aoff[4], boff[4], cp16[2];
  #pragma unroll
  for (int m = 0; m < 4; ++m) aoff[m] = (wr * 64 + m * 16 + l15) * 128;
  #pragma unroll
  for (int n = 0; n < 4; ++n) boff[n] = 32768 + (wc * 64 + n * 16 + l15) * 128;
  cp16[0] = ((0 + l4) ^ (l15 & 7)) * 16;
  cp16[1] = ((4 + l4) ^ (l15 & 7)) * 16;

  f32x4 acc[4][4] = {};
  const int NT = Kdim >> 6;
  char* lbase = (char*)lds4;

  // prologue: stage tiles 0 and 1 (6 issues each, FIFO order A0..A3,B0,B1)
  {
    char* s0 = lbase;
    char* s1 = lbase + SLOT;
    #pragma unroll
    for (int i = 0; i < 4; ++i) gld16(Ab + gaoff[i],      s0 + (i * 512 + w * 64) * 16);
    #pragma unroll
    for (int j = 0; j < 2; ++j) gld16(Bb + gboff[j],      s0 + 32768 + (j * 512 + w * 64) * 16);
    #pragma unroll
    for (int i = 0; i < 4; ++i) gld16(Ab + gaoff[i] + 64, s1 + (i * 512 + w * 64) * 16);
    #pragma unroll
    for (int j = 0; j < 2; ++j) gld16(Bb + gboff[j] + 64, s1 + 32768 + (j * 512 + w * 64) * 16);
  }

  int s = 0;
  for (int T = 0; T < NT; ++T) {
    const bool st  = (T + 2 < NT);
    const size_t kk = (size_t)(T + 2) * 64;
    const char* rA = lbase + s * SLOT;
    char* wS = lbase + ((s + 2 >= 3) ? (s - 1) : (s + 2)) * SLOT;

    if (T == NT - 1) asm volatile("s_waitcnt vmcnt(0)" ::: "memory");
    else             asm volatile("s_waitcnt vmcnt(6)" ::: "memory");
    __builtin_amdgcn_s_barrier();
    __builtin_amdgcn_sched_barrier(0);   // no read may hoist above the barrier

    bf16x8 b0, b1, b2, b3, a0, a1;

    // ---- phase 0: ks=0, mi {0,1}; stage A chunks 0,1 of tile T+2 ----------
    b0 = RD16(rA + boff[0] + cp16[0]);
    b1 = RD16(rA + boff[1] + cp16[0]);
    b2 = RD16(rA + boff[2] + cp16[0]);
    b3 = RD16(rA + boff[3] + cp16[0]);
    a0 = RD16(rA + aoff[0] + cp16[0]);
    a1 = RD16(rA + aoff[1] + cp16[0]);
    if (st) {
      gld16(Ab + gaoff[0] + kk, wS + (0 * 512 + w * 64) * 16);
      gld16(Ab + gaoff[1] + kk, wS + (1 * 512 + w * 64) * 16);
    }
    __builtin_amdgcn_s_barrier();
    asm volatile("s_waitcnt lgkmcnt(0)" ::: "memory");
    __builtin_amdgcn_sched_barrier(0);
    __builtin_amdgcn_s_setprio(1);
    acc[0][0] = MFMA16(a0, b0, acc[0][0]);
    acc[0][1] = MFMA16(a0, b1, acc[0][1]);
    acc[0][2] = MFMA16(a0, b2, acc[0][2]);
    acc[0][3] = MFMA16(a0, b3, acc[0][3]);
    acc[1][0] = MFMA16(a1, b0, acc[1][0]);
    acc[1][1] = MFMA16(a1, b1, acc[1][1]);
    acc[1][2] = MFMA16(a1, b2, acc[1][2]);
    acc[1][3] = MFMA16(a1, b3, acc[1][3]);
    __builtin_amdgcn_s_setprio(0);

    // ---- phase 1: ks=0, mi {2,3}; stage A chunks 2,3 ----------------------
    a0 = RD16(rA + aoff[2] + cp16[0]);
    a1 = RD16(rA + aoff[3] + cp16[0]);
    if (st) {
      gld16(Ab + gaoff[2] + kk, wS + (2 * 512 + w * 64) * 16);
      gld16(Ab + gaoff[3] + kk, wS + (3 * 512 + w * 64) * 16);
    }
    __builtin_amdgcn_s_barrier();
    asm volatile("s_waitcnt lgkmcnt(0)" ::: "memory");
    __builtin_amdgcn_sched_barrier(0);
    __builtin_amdgcn_s_setprio(1);
    acc[2][0] = MFMA16(a0, b0, acc[2][0]);
    acc[2][1] = MFMA16(a0, b1, acc[2][1]);
    acc[2][2] = MFMA16(a0, b2, acc[2][2]);
    acc[2][3] = MFMA16(a0, b3, acc[2][3]);
    acc[3][0] = MFMA16(a1, b0, acc[3][0]);
    acc[3][1] = MFMA16(a1, b1, acc[3][1]);
    acc[3][2] = MFMA16(a1, b2, acc[3][2]);
    acc[3][3] = MFMA16(a1, b3, acc[3][3]);
    __builtin_amdgcn_s_setprio(0);

    // ---- phase 2: ks=1, mi {0,1}; stage B chunk 0 --------------------------
    b0 = RD16(rA + boff[0] + cp16[1]);
    b1 = RD16(rA + boff[1] + cp16[1]);
    b2 = RD16(rA + boff[2] + cp16[1]);
    b3 = RD16(rA + boff[3] + cp16[1]);
    a0 = RD16(rA + aoff[0] + cp16[1]);
    a1 = RD16(rA + aoff[1] + cp16[1]);
    if (st) {
      gld16(Bb + gboff[0] + kk, wS + 32768 + (0 * 512 + w * 64) * 16);
    }
    __builtin_amdgcn_s_barrier();
    asm volatile("s_waitcnt lgkmcnt(0)" ::: "memory");
    __builtin_amdgcn_sched_barrier(0);
    __builtin_amdgcn_s_setprio(1);
    acc[0][0] = MFMA16(a0, b0, acc[0][0]);
    acc[0][1] = MFMA16(a0, b1, acc[0][1]);
    acc[0][2] = MFMA16(a0, b2, acc[0][2]);
    acc[0][3] = MFMA16(a0, b3, acc[0][3]);
    acc[1][0] = MFMA16(a1, b0, acc[1][0]);
    acc[1][1] = MFMA16(a1, b1, acc[1][1]);
    acc[1][2] = MFMA16(a1, b2, acc[1][2]);
    acc[1][3] = MFMA16(a1, b3, acc[1][3]);
    __builtin_amdgcn_s_setprio(0);

    // ---- phase 3: ks=1, mi {2,3}; stage B chunk 1 --------------------------
    a0 = RD16(rA + aoff[2] + cp16[1]);
    a1 = RD16(rA + aoff[3] + cp16[1]);
    if (st) {
      gld16(Bb + gboff[1] + kk, wS + 32768 + (1 * 512 + w * 64) * 16);
    }
    __builtin_amdgcn_s_barrier();
    asm volatile("s_waitcnt lgkmcnt(0)" ::: "memory");
    __builtin_amdgcn_sched_barrier(0);
    __builtin_amdgcn_s_setprio(1);
    acc[2][0] = MFMA16(a0, b0, acc[2][0]);
    acc[2][1] = MFMA16(a0, b1, acc[2][1]);
    acc[2][2] = MFMA16(a0, b2, acc[2][2]);
    acc[2][3] = MFMA16(a0, b3, acc[2][3]);
    acc[3][0] = MFMA16(a1, b0, acc[3][0]);
    acc[3][1] = MFMA16(a1, b1, acc[3][1]);
    acc[3][2] = MFMA16(a1, b2, acc[3][2]);
    acc[3][3] = MFMA16(a1, b3, acc[3][3]);
    __builtin_amdgcn_s_setprio(0);

    s = (s + 1 == 3) ? 0 : s + 1;
  }

  // ---- epilogue: C/D layout col=lane&15, row=(lane>>4)*4+reg (m89) --------
  const int bm0 = by * 256 + wr * 64;
  const int bn0 = bx * 128 + wc * 64;
  float* Cf = (float*)C;
  u16*   Ch = (u16*)C;
  #pragma unroll
  for (int mi = 0; mi < 4; ++mi) {
    #pragma unroll
    for (int ni = 0; ni < 4; ++ni) {
      const int col = bn0 + ni * 16 + l15;
      const int r0  = bm0 + mi * 16 + l4 * 4;
      float bv = 0.f;
      if (EPI == 0 || EPI == 3 || EPI == 4) bv = bias[col];
      #pragma unroll
      for (int r = 0; r < 4; ++r) {
        const size_t idx = (size_t)blockIdx.z * cstr + (size_t)(r0 + r) * ldc + col;
        const float v = acc[mi][ni][r];
        if      (EPI == 0) Ch[idx] = f2bf(v + bv);
        else if (EPI == 1) Cf[idx] = v * scale;
        else if (EPI == 2) Cf[idx] = v + add[idx];
        else if (EPI == 3) Ch[idx] = f2bf(fmaxf(v + bv, 0.f));
        else               Cf[idx] = v + bv + add[idx];
      }
    }
  }
}

// ---------------------------------------------------------------------------
// LayerNorm row kernel: x f32 [rows][1024] -> bf16 out
// ---------------------------------------------------------------------------
__global__ __launch_bounds__(256) void ln_kernel(
    const float* __restrict__ x, const float* __restrict__ g,
    const float* __restrict__ be, u16* __restrict__ out)
{
  const int row = blockIdx.x;
  const int tid = threadIdx.x;
  const float4 v = ((const float4*)(x + (size_t)row * EMBED))[tid];
  float s  = v.x + v.y + v.z + v.w;
  float s2 = v.x * v.x + v.y * v.y + v.z * v.z + v.w * v.w;
  #pragma unroll
  for (int m = 1; m < 64; m <<= 1) { s += __shfl_xor(s, m); s2 += __shfl_xor(s2, m); }
  __shared__ float ls[4], ls2[4];
  const int w = tid >> 6;
  if ((tid & 63) == 0) { ls[w] = s; ls2[w] = s2; }
  __syncthreads();
  s  = ls[0] + ls[1] + ls[2] + ls[3];
  s2 = ls2[0] + ls2[1] + ls2[2] + ls2[3];
  const float mu   = s * (1.f / EMBED);
  const float var  = s2 * (1.f / EMBED) - mu * mu;
  const float rstd = rsqrtf(var + 1e-5f);
  const float4 gv = ((const float4*)g)[tid];
  const float4 bv = ((const float4*)be)[tid];
  ushort4 o;
  o.x = f2bf((v.x - mu) * rstd * gv.x + bv.x);
  o.y = f2bf((v.y - mu) * rstd * gv.y + bv.y);
  o.z = f2bf((v.z - mu) * rstd * gv.z + bv.z);
  o.w = f2bf((v.w - mu) * rstd * gv.w + bv.w);
  ((ushort4*)(out + (size_t)row * EMBED))[tid] = o;
}

// ---------------------------------------------------------------------------
// Row softmax: S f32 [2048] -> P bf16
// ---------------------------------------------------------------------------
__global__ __launch_bounds__(256) void softmax_kernel(
    const float* __restrict__ S, u16* __restrict__ P)
{
  const int tid = threadIdx.x;
  const size_t base = ((size_t)blockIdx.y * SEQ + blockIdx.x) * SEQ;
  const float4* src = (const float4*)(S + base);
  float4 a = src[tid];
  float4 b = src[tid + 256];
  float m = fmaxf(fmaxf(fmaxf(a.x, a.y), fmaxf(a.z, a.w)),
                  fmaxf(fmaxf(b.x, b.y), fmaxf(b.z, b.w)));
  #pragma unroll
  for (int msk = 1; msk < 64; msk <<= 1) m = fmaxf(m, __shfl_xor(m, msk));
  __shared__ float red[8];
  const int w = tid >> 6;
  if ((tid & 63) == 0) red[w] = m;
  __syncthreads();
  m = fmaxf(fmaxf(red[0], red[1]), fmaxf(red[2], red[3]));
  a.x = __expf(a.x - m); a.y = __expf(a.y - m); a.z = __expf(a.z - m); a.w = __expf(a.w - m);
  b.x = __expf(b.x - m); b.y = __expf(b.y - m); b.z = __expf(b.z - m); b.w = __expf(b.w - m);
  float s = a.x + a.y + a.z + a.w + b.x + b.y + b.z + b.w;
  #pragma unroll
  for (int msk = 1; msk < 64; msk <<= 1) s += __shfl_xor(s, msk);
  if ((tid & 63) == 0) red[4 + w] = s;
  __syncthreads();
  s = red[4] + red[5] + red[6] + red[7];
  const float inv = 1.0f / s;
  ushort4 oa, ob;
  oa.x = f2bf(a.x * inv); oa.y = f2bf(a.y * inv); oa.z = f2bf(a.z * inv); oa.w = f2bf(a.w * inv);
  ob.x = f2bf(b.x * inv); ob.y = f2bf(b.y * inv); ob.z = f2bf(b.z * inv); ob.w = f2bf(b.w * inv);
  ushort4* dst = (ushort4*)(P + base);
  dst[tid]       = oa;
  dst[tid + 256] = ob;
}

// ---------------------------------------------------------------------------
// Transpose + cast: W f32 [K][N] -> Wt bf16 [N][K]
// ---------------------------------------------------------------------------
__global__ void transpose_cast_f32(const float* __restrict__ W, u16* __restrict__ Wt,
                                   int K, int N)
{
  __shared__ float t[32][33];
  const int tx = threadIdx.x, ty = threadIdx.y;     // 32 x 8
  const int n0 = blockIdx.x * 32, k0 = blockIdx.y * 32;
  #pragma unroll
  for (int i = 0; i < 4; ++i)
    t[ty + i * 8][tx] = W[(size_t)(k0 + ty + i * 8) * N + n0 + tx];
  __syncthreads();
  #pragma unroll
  for (int i = 0; i < 4; ++i)
    Wt[(size_t)(n0 + ty + i * 8) * K + k0 + tx] = f2bf(t[tx][ty + i * 8]);
}

// Transpose bf16 slice: src [SEQ][sld] (batch stride sstr) -> dst [EMBED][SEQ]
__global__ void transpose_bf16(const u16* __restrict__ V, u16* __restrict__ Vt,
                               int sld, long long sstr, long long dstr)
{
  __shared__ u16 t[32][33];
  const int tx = threadIdx.x, ty = threadIdx.y;
  const int d0 = blockIdx.x * 32, s0 = blockIdx.y * 32;
  const size_t so = (size_t)blockIdx.z * sstr;
  const size_t do_ = (size_t)blockIdx.z * dstr;
  #pragma unroll
  for (int i = 0; i < 4; ++i)
    t[ty + i * 8][tx] = V[so + (size_t)(s0 + ty + i * 8) * sld + d0 + tx];
  __syncthreads();
  #pragma unroll
  for (int i = 0; i < 4; ++i)
    Vt[do_ + (size_t)(d0 + ty + i * 8) * SEQ + s0 + tx] = t[tx][ty + i * 8];
}

__global__ void concat_bias(const float* __restrict__ a, const float* __restrict__ b,
                            const float* __restrict__ c, float* __restrict__ o)
{
  const int i = blockIdx.x * 1024 + threadIdx.x;
  o[i] = (i < 1024) ? a[i] : (i < 2048) ? b[i - 1024] : c[i - 2048];
}

// ---------------------------------------------------------------------------
extern "C" void kernel_launch(void* const* d_in, const int* in_sizes, int n_in,
                              void* d_out, int out_size, void* d_ws, size_t ws_size,
                              hipStream_t stream)
{
  const float* x   = (const float*)d_in[0];
  const float* Wq  = (const float*)d_in[1];
  const float* bq  = (const float*)d_in[2];
  const float* Wk  = (const float*)d_in[3];
  const float* bk  = (const float*)d_in[4];
  const float* Wv  = (const float*)d_in[5];
  const float* bv  = (const float*)d_in[6];
  const float* W1  = (const float*)d_in[7];
  const float* b1  = (const float*)d_in[8];
  const float* W2  = (const float*)d_in[9];
  const float* b2  = (const float*)d_in[10];
  const float* g1  = (const float*)d_in[11];
  const float* be1 = (const float*)d_in[12];
  const float* g2  = (const float*)d_in[13];
  const float* be2 = (const float*)d_in[14];
  float* out = (float*)d_out;

  const size_t RD = (size_t)NB * SEQ * EMBED;    // 8.4M

  char* base = (char*)d_ws;
  size_t o = 0;
  auto alloc = [&](size_t bytes) -> void* {
    o = (o + 255) & ~(size_t)255;
    void* p = base + o;
    o += bytes;
    return p;
  };

  u16*   wqkvT = (u16*)alloc((size_t)3 * EMBED * EMBED * 2);  // [3072][1024]
  u16*   w1T   = (u16*)alloc((size_t)HID * EMBED * 2);        // [4096][1024]
  u16*   w2T   = (u16*)alloc((size_t)EMBED * HID * 2);        // [1024][4096]
  float* bqkv  = (float*)alloc(3072 * 4);
  u16*   h     = (u16*)alloc(RD * 2);
  u16*   QKV   = (u16*)alloc(RD * 3 * 2);                     // [8192][3072]
  u16*   Vt    = (u16*)alloc(RD * 2);                         // [4][1024][2048]
  float* x2    = (float*)alloc(RD * 4);

  // batched attention scratch if workspace allows, else per-batch sequential
  const size_t need_batched = o + (size_t)NB * SEQ * SEQ * 6 + 1024;
  const int NZ = (ws_size >= need_batched) ? NB : 1;
  float* Sbuf = (float*)alloc((size_t)NZ * SEQ * SEQ * 4);
  u16*   Pb   = (u16*)alloc((size_t)NZ * SEQ * SEQ * 2);
  u16*   ff   = (NZ == NB) ? (u16*)Sbuf                       // 67MB alias
                           : (u16*)alloc((size_t)NB * SEQ * HID * 2);

  const dim3 blk(512);
  const dim3 tblk(32, 8);

  // 1) weights -> bf16 [N][K]; QKV weights fused row-wise
  transpose_cast_f32<<<dim3(32, 32), tblk, 0, stream>>>(Wq, wqkvT, EMBED, EMBED);
  transpose_cast_f32<<<dim3(32, 32), tblk, 0, stream>>>(Wk, wqkvT + (size_t)EMBED * EMBED, EMBED, EMBED);
  transpose_cast_f32<<<dim3(32, 32), tblk, 0, stream>>>(Wv, wqkvT + (size_t)2 * EMBED * EMBED, EMBED, EMBED);
  transpose_cast_f32<<<dim3(HID / 32, EMBED / 32), tblk, 0, stream>>>(W1, w1T, EMBED, HID);
  transpose_cast_f32<<<dim3(EMBED / 32, HID / 32), tblk, 0, stream>>>(W2, w2T, HID, EMBED);
  concat_bias<<<dim3(3), dim3(1024), 0, stream>>>(bq, bk, bv, bqkv);

  // 2) LN1
  ln_kernel<<<dim3(NB * SEQ), dim3(256), 0, stream>>>(x, g1, be1, h);

  // 3) fused QKV projection: [8192][3072]
  gemm8p<0><<<dim3(3072 / 128, NB * SEQ / 256, 1), blk, 0, stream>>>(
      h, EMBED, 0LL, wqkvT, EMBED, 0LL, QKV, 3072, 0LL, bqkv, nullptr, 1.f, EMBED);

  // 4) V slice -> Vt [1024][2048] per batch
  transpose_bf16<<<dim3(EMBED / 32, SEQ / 32, NB), tblk, 0, stream>>>(
      QKV + 2048, Vt, 3072, (long long)SEQ * 3072, (long long)EMBED * SEQ);

  // 5) attention
  for (int b = 0; b < NB; b += NZ) {
    const u16* Qp  = QKV + (size_t)b * SEQ * 3072;
    const u16* Kp  = Qp + 1024;
    const u16* Vtp = Vt + (size_t)b * EMBED * SEQ;
    float* x2p     = x2 + (size_t)b * SEQ * EMBED;
    const float* xp = x + (size_t)b * SEQ * EMBED;
    gemm8p<1><<<dim3(SEQ / 128, SEQ / 256, NZ), blk, 0, stream>>>(
        Qp, 3072, (long long)SEQ * 3072, Kp, 3072, (long long)SEQ * 3072,
        Sbuf, SEQ, (long long)SEQ * SEQ, nullptr, nullptr, 0.03125f, EMBED);
    softmax_kernel<<<dim3(SEQ, NZ), dim3(256), 0, stream>>>(Sbuf, Pb);
    gemm8p<2><<<dim3(EMBED / 128, SEQ / 256, NZ), blk, 0, stream>>>(
        Pb, SEQ, (long long)SEQ * SEQ, Vtp, SEQ, (long long)EMBED * SEQ,
        x2p, EMBED, (long long)SEQ * EMBED, nullptr, xp, 1.f, SEQ);
  }

  // 6) LN2
  ln_kernel<<<dim3(NB * SEQ), dim3(256), 0, stream>>>(x2, g2, be2, h);

  // 7) MLP
  gemm8p<3><<<dim3(HID / 128, NB * SEQ / 256, 1), blk, 0, stream>>>(
      h, EMBED, 0LL, w1T, EMBED, 0LL, ff, HID, 0LL, b1, nullptr, 1.f, EMBED);
  gemm8p<4><<<dim3(EMBED / 128, NB * SEQ / 256, 1), blk, 0, stream>>>(
      ff, HID, 0LL, w2T, HID, 0LL, out, EMBED, 0LL, b2, x2, 1.f, HID);
}